// Round 1
// baseline (69.169 us; speedup 1.0000x reference)
//
#include <hip/hip_runtime.h>
#include <math.h>

// Dendrite: B=8192, D=32, S=8, M=255.
// out[b,d] = lin_b + sum_{v=1..255} lin_w[v-1] * prod_{i: bit i of v} s[b,d,7-i]
// s[b,d,j] = sigmoid(k[d,j]*(w[d,j]*x[b,j] - q[d,j]))
// Subset products factor over nibbles: P(v) = Phi[v>>4] * Plo[v&15].
//
// v5: packed-fp32 bilinear form + x2 thread coarsening.
//  - T stored in LDS as interleaved row-PAIRS: s_t2[(p*16+l)*2+e] = T[2p+e][l]
//    so each ds_read_b128 yields two natural (row 2p, row 2p+1) v2f pairs that
//    feed v_pk_fma_f32 directly (no splat of the LDS operand needed).
//  - Plo is built as splat-pairs via a packed DP chain (15 v_pk_mul); Phi is
//    built scalar then packed into true (Phi[2p],Phi[2p+1]) pairs.
//  - Each thread computes 2 outputs (gid, gid+256): same d -> k/w/q loads and
//    all 64 T-row reads are shared across both outputs (32 LDS b128/output).
// Issue count per output drops ~350 scalar VALU -> ~195 mostly-packed ops.

typedef float v2f __attribute__((ext_vector_type(2)));

#define BLOCK 256
#define OUTS_PER_BLOCK 512   // 2 outputs per thread

__global__ __launch_bounds__(BLOCK, 2) void dendrite_kernel(
    const float* __restrict__ x,      // [B,1,S]
    const float* __restrict__ k,      // [D,S]
    const float* __restrict__ w,      // [D,S]
    const float* __restrict__ q,      // [D,S]
    const float* __restrict__ lin_w,  // [1,M], M=255
    const float* __restrict__ lin_b,  // [1]
    float* __restrict__ out)          // [B,1,D]
{
    // Interleaved weight table: t[v] = (v==0 ? 0 : lin_w[v-1]), T[h][l]=t[16h+l].
    // s_t2[(p<<5) + (l<<1) + e] = T[2p+e][l],  p=0..7, l=0..15, e=0..1.
    __shared__ float s_t2[256];

    const int tid = threadIdx.x;
    {
        const float tv = (tid == 0) ? 0.0f : lin_w[tid - 1];
        const int p = tid >> 5;          // h>>1,  h = tid>>4
        const int e = (tid >> 4) & 1;    // h&1
        const int l = tid & 15;
        s_t2[(p << 5) + (l << 1) + e] = tv;
    }
    __syncthreads();

    const int gid0 = blockIdx.x * OUTS_PER_BLOCK + tid;
    const int gid1 = gid0 + BLOCK;           // +256 -> b1 = b0+8, same d
    const int b0 = gid0 >> 5;
    const int d  = gid0 & 31;

    // x rows: 32B each, broadcast across the 32 d-lanes (L1).
    const float4* xv0 = (const float4*)(x + (size_t)b0 * 8);
    const float4 xa0 = xv0[0], xb0 = xv0[1];
    const float4* xv1 = (const float4*)(x + (size_t)(b0 + 8) * 8);
    const float4 xa1 = xv1[0], xb1 = xv1[1];
    // k/w/q rows: lanes 0..31 cover 1KB contiguous -> coalesced, L1-resident.
    const float4* kv = (const float4*)(k + d * 8);
    const float4 ka = kv[0], kb = kv[1];
    const float4* wv = (const float4*)(w + d * 8);
    const float4 wa = wv[0], wb = wv[1];
    const float4* qv = (const float4*)(q + d * 8);
    const float4 qa = qv[0], qb = qv[1];

    const float xx0[8] = {xa0.x, xa0.y, xa0.z, xa0.w, xb0.x, xb0.y, xb0.z, xb0.w};
    const float xx1[8] = {xa1.x, xa1.y, xa1.z, xa1.w, xb1.x, xb1.y, xb1.z, xb1.w};
    const float kk[8]  = {ka.x, ka.y, ka.z, ka.w, kb.x, kb.y, kb.z, kb.w};
    const float ww[8]  = {wa.x, wa.y, wa.z, wa.w, wb.x, wb.y, wb.z, wb.w};
    const float qq[8]  = {qa.x, qa.y, qa.z, qa.w, qb.x, qb.y, qb.z, qb.w};

    // sigmoids for both samples
    float s0v[8], s1v[8];
#pragma unroll
    for (int j = 0; j < 8; ++j) {
        const float z0 = kk[j] * fmaf(ww[j], xx0[j], -qq[j]);
        const float z1 = kk[j] * fmaf(ww[j], xx1[j], -qq[j]);
        s0v[j] = __builtin_amdgcn_rcpf(1.0f + __expf(-z0));
        s1v[j] = __builtin_amdgcn_rcpf(1.0f + __expf(-z1));
    }

    // Subset-product DP per nibble (fully unrolled, constant indices).
    // high-nibble bit i' -> s[3-i']; low-nibble bit i -> s[7-i]
    // Plo kept as splat-pairs (v2f) so the main loop is pure v_pk_fma_f32.
    float Phi0[16], Phi1[16];
    v2f   Plo0[16], Plo1[16];
    Phi0[0] = 1.0f; Phi1[0] = 1.0f;
    Plo0[0] = (v2f){1.0f, 1.0f};
    Plo1[0] = (v2f){1.0f, 1.0f};
#pragma unroll
    for (int v = 1; v < 16; ++v) {
        const int lb  = v & (-v);
        const int idx = (lb == 1) ? 0 : (lb == 2) ? 1 : (lb == 4) ? 2 : 3;
        Phi0[v] = Phi0[v ^ lb] * s0v[3 - idx];
        Phi1[v] = Phi1[v ^ lb] * s1v[3 - idx];
        Plo0[v] = Plo0[v ^ lb] * s0v[7 - idx];   // splat-pair * scalar
        Plo1[v] = Plo1[v ^ lb] * s1v[7 - idx];
    }

    // True row-pairs of Phi: (Phi[2p], Phi[2p+1])
    v2f phi0p[8], phi1p[8];
#pragma unroll
    for (int p = 0; p < 8; ++p) {
        phi0p[p] = (v2f){Phi0[2 * p], Phi0[2 * p + 1]};
        phi1p[p] = (v2f){Phi1[2 * p], Phi1[2 * p + 1]};
    }

    // acc = sum_p (Phi[2p],Phi[2p+1]) .* sum_l (T[2p][l],T[2p+1][l]) * Plo[l]
    // 8 wave-uniform ds_read_b128 per p (broadcast), shared by both outputs.
    v2f acc0 = {0.0f, 0.0f};
    v2f acc1 = {0.0f, 0.0f};
#pragma unroll
    for (int p = 0; p < 8; ++p) {
        const float4* row = (const float4*)(s_t2 + (p << 5));
        const float4 r0 = row[0], r1 = row[1], r2 = row[2], r3 = row[3];
        const float4 r4 = row[4], r5 = row[5], r6 = row[6], r7 = row[7];
        const v2f pr[16] = {
            {r0.x, r0.y}, {r0.z, r0.w}, {r1.x, r1.y}, {r1.z, r1.w},
            {r2.x, r2.y}, {r2.z, r2.w}, {r3.x, r3.y}, {r3.z, r3.w},
            {r4.x, r4.y}, {r4.z, r4.w}, {r5.x, r5.y}, {r5.z, r5.w},
            {r6.x, r6.y}, {r6.z, r6.w}, {r7.x, r7.y}, {r7.z, r7.w}};
        // two independent 8-deep chains per sample for ILP
        v2f i0a = {0.0f, 0.0f}, i0b = {0.0f, 0.0f};
        v2f i1a = {0.0f, 0.0f}, i1b = {0.0f, 0.0f};
#pragma unroll
        for (int l = 0; l < 8; ++l) {
            i0a += pr[l] * Plo0[l];
            i1a += pr[l] * Plo1[l];
            i0b += pr[l + 8] * Plo0[l + 8];
            i1b += pr[l + 8] * Plo1[l + 8];
        }
        acc0 += phi0p[p] * (i0a + i0b);
        acc1 += phi1p[p] * (i1a + i1b);
    }

    const float bias = lin_b[0];
    out[gid0] = acc0.x + acc0.y + bias;
    out[gid1] = acc1.x + acc1.y + bias;
}

extern "C" void kernel_launch(void* const* d_in, const int* in_sizes, int n_in,
                              void* d_out, int out_size, void* d_ws, size_t ws_size,
                              hipStream_t stream) {
    // setup_inputs order: x, k, w, q, mask, lin_w, lin_b
    const float* x     = (const float*)d_in[0];
    const float* k     = (const float*)d_in[1];
    const float* w     = (const float*)d_in[2];
    const float* q     = (const float*)d_in[3];
    // d_in[4] = mask: binary expansions of 1..255, structure exploited, unused
    const float* lin_w = (const float*)d_in[5];
    const float* lin_b = (const float*)d_in[6];
    float* out = (float*)d_out;

    const int total = out_size;                 // B*D = 262144, multiple of 512
    const int grid  = total / OUTS_PER_BLOCK;   // 512 blocks, 2 wg/CU
    dendrite_kernel<<<grid, BLOCK, 0, stream>>>(x, k, w, q, lin_w, lin_b, out);
}